// Round 5
// baseline (280.144 us; speedup 1.0000x reference)
//
#include <hip/hip_runtime.h>
#include <hip/hip_cooperative_groups.h>

namespace cg = cooperative_groups;

// Problem constants: B=64, NIN=512, H1=1024, H2=1024, NOUT=512, COND=64, FC=1.
#define BB    64
#define NIN   512
#define H1D   1024
#define H2D   1024
#define NOUTD 512
#define CONDD 64
#define L2E   1.4426950408889634f   // log2(e)

struct Params {
    const float *x, *u, *m0, *m1, *m2, *W0, *W1, *W2;
    const float *a0w, *a0b, *b0w, *b0b;
    const float *a1w, *a1b, *b1w, *b1b;
    const float *a2w, *a2b, *b2w, *b2b;
    float *AX0, *AX1, *AX2, *C0t, *C1t, *C2t, *out;
};

// ---------------------------------------------------------------------------
// Gated masked matvec phase (branchless):
//   out[o,b] = sum_i 1/(1+2^(-A'[i,b]*Ct[o,b])) * (m!=0 ? W : 0)[o,i] * X[i,b]
// Block: 8 waves split I 8-ways; OT o's per block; LDS reduce; plain store.
// m/W loads are wave-uniform s_loads; the mask select is scalar s_cselect.
// ---------------------------------------------------------------------------
template<int I, int OT, bool FINAL>
__device__ __forceinline__ void gated_phase(
    const float2* __restrict__ AX, const float* __restrict__ Ct,
    const float*  __restrict__ M,  const float* __restrict__ W,
    float* __restrict__ out, float (*red)[4][64],
    int b, int wid, int tid)
{
    constexpr int ICW = I / 8;                  // i extent per wave
    const int o0    = blockIdx.x * OT;
    const int ibase = wid * ICW;

    float cc[OT], acc[OT];
    const float* __restrict__ mrow[OT];
    const float* __restrict__ wrow[OT];
    #pragma unroll
    for (int oo = 0; oo < OT; ++oo) {
        cc[oo]   = Ct[(o0 + oo) * 64 + b];
        mrow[oo] = M + (size_t)(o0 + oo) * I + ibase;
        wrow[oo] = W + (size_t)(o0 + oo) * I + ibase;
        acc[oo]  = 0.f;
    }
    const float2* __restrict__ axp = AX + (size_t)ibase * 64 + b;

    #pragma unroll 8
    for (int ii = 0; ii < ICW; ++ii) {
        const float2 ax = axp[(size_t)ii * 64];
        #pragma unroll
        for (int oo = 0; oo < OT; ++oo) {
            // uniform mask select on the scalar pipe (no VALU mul for m*W)
            const unsigned mb = __float_as_uint(mrow[oo][ii]);
            const unsigned wb = __float_as_uint(wrow[oo][ii]);
            const float mw = __uint_as_float(mb ? wb : 0u);
            const float t  = __builtin_amdgcn_exp2f(-(ax.x * cc[oo]));
            const float s  = __builtin_amdgcn_rcpf(1.f + t);    // inf-safe -> 0
            acc[oo] = fmaf(s, mw * ax.y, acc[oo]);
        }
    }

    #pragma unroll
    for (int oo = 0; oo < OT; ++oo) red[wid][oo][b] = acc[oo];
    __syncthreads();
    if (tid < OT * 64) {
        const int oo = tid >> 6, bb = tid & 63;
        float v = 0.f;
        #pragma unroll
        for (int w8 = 0; w8 < 8; ++w8) v += red[w8][oo][bb];
        if (FINAL) out[bb * NOUTD + (o0 + oo)] = v;             // (B, NOUT)
        else       out[((o0 + oo) * 64 + bb) * 2 + 1] = v;      // next AX .y
    }
}

// ---------------------------------------------------------------------------
// Fused end-to-end kernel: prep GEMMs + x-transpose, then 3 gated layers,
// grid-synced. 256 blocks x 512 threads = 8 waves/CU, co-resident.
// ---------------------------------------------------------------------------
__global__ __launch_bounds__(512, 1) void fused_kernel(Params p)
{
    cg::grid_group grid = cg::this_grid();
    __shared__ float uT[64 * 65];
    __shared__ float red[8][4][64];

    const int tid = threadIdx.x;
    const int b   = tid & 63;
    const int wid = __builtin_amdgcn_readfirstlane(tid >> 6);   // 0..7 uniform

    // ---- Phase 0: six cond GEMMs (rows concat [A0|C0|A1|C1|A2|C2]) + x^T ----
    for (int e = tid; e < BB * CONDD; e += 512)
        uT[(e & 63) * 65 + (e >> 6)] = p.u[e];   // uT[k*65+b] = u[b*64+k]
    __syncthreads();

    const int gw = blockIdx.x * 8 + wid;         // global wave id, 0..2047
    if (gw < 1280) {
        const int r0 = gw * 4;                   // 4 rows/wave, never straddles seg
        const float* w; const float* bias; float* outp; int stride; float scale; int lr0;
        if      (r0 <  512) { w = p.a0w; bias = p.a0b; outp = p.AX0; stride = 2; scale = L2E; lr0 = r0;        }
        else if (r0 < 1536) { w = p.b0w; bias = p.b0b; outp = p.C0t; stride = 1; scale = 1.f; lr0 = r0 -  512; }
        else if (r0 < 2560) { w = p.a1w; bias = p.a1b; outp = p.AX1; stride = 2; scale = L2E; lr0 = r0 - 1536; }
        else if (r0 < 3584) { w = p.b1w; bias = p.b1b; outp = p.C1t; stride = 1; scale = 1.f; lr0 = r0 - 2560; }
        else if (r0 < 4608) { w = p.a2w; bias = p.a2b; outp = p.AX2; stride = 2; scale = L2E; lr0 = r0 - 3584; }
        else                { w = p.b2w; bias = p.b2b; outp = p.C2t; stride = 1; scale = 1.f; lr0 = r0 - 4608; }

        const float* __restrict__ w0 = w + (lr0 + 0) * CONDD;
        const float* __restrict__ w1 = w + (lr0 + 1) * CONDD;
        const float* __restrict__ w2 = w + (lr0 + 2) * CONDD;
        const float* __restrict__ w3 = w + (lr0 + 3) * CONDD;
        float acc0 = bias[lr0 + 0], acc1 = bias[lr0 + 1];
        float acc2 = bias[lr0 + 2], acc3 = bias[lr0 + 3];
        #pragma unroll
        for (int k = 0; k < CONDD; ++k) {
            const float uv = uT[k * 65 + b];
            acc0 = fmaf(w0[k], uv, acc0);
            acc1 = fmaf(w1[k], uv, acc1);
            acc2 = fmaf(w2[k], uv, acc2);
            acc3 = fmaf(w3[k], uv, acc3);
        }
        outp[((lr0 + 0) * 64 + b) * stride] = acc0 * scale;
        outp[((lr0 + 1) * 64 + b) * stride] = acc1 * scale;
        outp[((lr0 + 2) * 64 + b) * stride] = acc2 * scale;
        outp[((lr0 + 3) * 64 + b) * stride] = acc3 * scale;
    } else if (gw < 1344) {
        // x transpose: 64 waves x 8 i's each; lane=b reads x[b][i] (gather),
        // writes AX0[i][b].y coalesced. Only 32K elements total.
        const int i0 = (gw - 1280) * 8;
        #pragma unroll
        for (int r = 0; r < 8; ++r)
            p.AX0[((i0 + r) * 64 + b) * 2 + 1] = p.x[b * NIN + i0 + r];
    }
    grid.sync();

    // ---- Layer 1: I=512,  O=1024, OT=4 ----
    gated_phase<NIN, 4, false>((const float2*)p.AX0, p.C0t, p.m0, p.W0,
                               p.AX1, red, b, wid, tid);
    grid.sync();

    // ---- Layer 2: I=1024, O=1024, OT=4 ----
    gated_phase<H1D, 4, false>((const float2*)p.AX1, p.C1t, p.m1, p.W1,
                               p.AX2, red, b, wid, tid);
    grid.sync();

    // ---- Layer 3: I=1024, O=512, OT=2, writes d_out (B, NOUT) ----
    gated_phase<H2D, 2, true>((const float2*)p.AX2, p.C2t, p.m2, p.W2,
                              p.out, red, b, wid, tid);
}

// ---------------------------------------------------------------------------
extern "C" void kernel_launch(void* const* d_in, const int* in_sizes, int n_in,
                              void* d_out, int out_size, void* d_ws, size_t ws_size,
                              hipStream_t stream) {
    (void)in_sizes; (void)n_in; (void)out_size; (void)ws_size;

    float* ws = (float*)d_ws;                  // offsets in floats
    Params p;
    p.x   = (const float*)d_in[0];
    p.u   = (const float*)d_in[1];
    p.m0  = (const float*)d_in[2];
    p.m1  = (const float*)d_in[3];
    p.m2  = (const float*)d_in[4];
    p.W0  = (const float*)d_in[5];
    p.W1  = (const float*)d_in[6];
    p.W2  = (const float*)d_in[7];
    p.a0w = (const float*)d_in[8];  p.a0b = (const float*)d_in[9];
    p.b0w = (const float*)d_in[10]; p.b0b = (const float*)d_in[11];
    p.a1w = (const float*)d_in[12]; p.a1b = (const float*)d_in[13];
    p.b1w = (const float*)d_in[14]; p.b1b = (const float*)d_in[15];
    p.a2w = (const float*)d_in[16]; p.a2b = (const float*)d_in[17];
    p.b2w = (const float*)d_in[18]; p.b2b = (const float*)d_in[19];
    p.AX0 = ws;                                // float2[512*64]   = 65536 f
    p.AX1 = ws + 65536;                        // float2[1024*64]  = 131072 f
    p.AX2 = ws + 196608;                       // float2[1024*64]  = 131072 f
    p.C0t = ws + 327680;                       // 1024*64
    p.C1t = ws + 393216;                       // 1024*64
    p.C2t = ws + 458752;                       // 512*64
    p.out = (float*)d_out;

    void* kargs[] = { (void*)&p };
    hipLaunchCooperativeKernel((void*)fused_kernel, dim3(256), dim3(512),
                               kargs, 0, stream);
}

// Round 6
// 155.250 us; speedup vs baseline: 1.8045x; 1.8045x over previous
//
#include <hip/hip_runtime.h>

// Problem constants: B=64, NIN=512, H1=1024, H2=1024, NOUT=512, COND=64, FC=1.
#define BB    64
#define NIN   512
#define H1D   1024
#define H2D   1024
#define NOUTD 512
#define CONDD 64
#define L2E   1.4426950408889634f   // log2(e)

// ---------------------------------------------------------------------------
// Prep kernel (identical to R4):
//   blocks [0,320): six cond GEMMs, 16 rows/block (4 rows/wave), rows
//                   concatenated [A0|C0|A1|C1|A2|C2] = 5120 rows.
//                   A-rows stored prescaled by log2(e) into AX .x (stride 2).
//   blocks [320,328): x transpose tiles -> AX0 .y
// ---------------------------------------------------------------------------
__global__ __launch_bounds__(256) void prep_kernel(
    const float* __restrict__ x,  const float* __restrict__ u,
    const float* __restrict__ a0w, const float* __restrict__ a0b,
    const float* __restrict__ b0w, const float* __restrict__ b0b,
    const float* __restrict__ a1w, const float* __restrict__ a1b,
    const float* __restrict__ b1w, const float* __restrict__ b1b,
    const float* __restrict__ a2w, const float* __restrict__ a2b,
    const float* __restrict__ b2w, const float* __restrict__ b2b,
    float* __restrict__ AX0, float* __restrict__ AX1, float* __restrict__ AX2,
    float* __restrict__ C0t, float* __restrict__ C1t, float* __restrict__ C2t)
{
    __shared__ float lds[64 * 65];
    const int tid = threadIdx.x;
    const int bid = blockIdx.x;

    if (bid < 320) {
        for (int e = tid; e < BB * CONDD; e += 256)
            lds[(e & 63) * 65 + (e >> 6)] = u[e];
        __syncthreads();

        const int b   = tid & 63;
        const int wid = __builtin_amdgcn_readfirstlane(tid >> 6);
        const int r0  = bid * 16 + wid * 4;

        const float* w; const float* bias; float* out; int stride; float scale; int lr0;
        if      (r0 <  512) { w = a0w; bias = a0b; out = AX0; stride = 2; scale = L2E; lr0 = r0;        }
        else if (r0 < 1536) { w = b0w; bias = b0b; out = C0t; stride = 1; scale = 1.f; lr0 = r0 -  512; }
        else if (r0 < 2560) { w = a1w; bias = a1b; out = AX1; stride = 2; scale = L2E; lr0 = r0 - 1536; }
        else if (r0 < 3584) { w = b1w; bias = b1b; out = C1t; stride = 1; scale = 1.f; lr0 = r0 - 2560; }
        else if (r0 < 4608) { w = a2w; bias = a2b; out = AX2; stride = 2; scale = L2E; lr0 = r0 - 3584; }
        else                { w = b2w; bias = b2b; out = C2t; stride = 1; scale = 1.f; lr0 = r0 - 4608; }

        const float* __restrict__ w0 = w + (lr0 + 0) * CONDD;
        const float* __restrict__ w1 = w + (lr0 + 1) * CONDD;
        const float* __restrict__ w2 = w + (lr0 + 2) * CONDD;
        const float* __restrict__ w3 = w + (lr0 + 3) * CONDD;
        float acc0 = bias[lr0 + 0], acc1 = bias[lr0 + 1];
        float acc2 = bias[lr0 + 2], acc3 = bias[lr0 + 3];
        #pragma unroll
        for (int k = 0; k < CONDD; ++k) {
            const float uv = lds[k * 65 + b];
            acc0 = fmaf(w0[k], uv, acc0);
            acc1 = fmaf(w1[k], uv, acc1);
            acc2 = fmaf(w2[k], uv, acc2);
            acc3 = fmaf(w3[k], uv, acc3);
        }
        out[((lr0 + 0) * 64 + b) * stride] = acc0 * scale;
        out[((lr0 + 1) * 64 + b) * stride] = acc1 * scale;
        out[((lr0 + 2) * 64 + b) * stride] = acc2 * scale;
        out[((lr0 + 3) * 64 + b) * stride] = acc3 * scale;
    } else {
        const int i0 = (bid - 320) * 64;
        for (int e = tid; e < 64 * 64; e += 256) {
            int r = e >> 6, c = e & 63;                // r=b, c=i offset
            lds[c * 65 + r] = x[r * NIN + i0 + c];
        }
        __syncthreads();
        for (int e = tid; e < 64 * 64; e += 256) {
            int r = e >> 6, c = e & 63;                // r=i offset, c=b
            AX0[((i0 + r) * 64 + c) * 2 + 1] = lds[r * 65 + c];
        }
    }
}

// ---------------------------------------------------------------------------
// Branchless gated masked matvec (R4 body, unchanged except OT):
//   out[o,b] = sum_i 1/(1+2^(-A'[i,b]*Ct[o,b])) * m[o,i]*W[o,i] * X[i,b]
// Block: 512 threads = 8 waves splitting I 8-ways; OT o's per block.
// launch_bounds(512,4) -> 2 blocks/CU co-resident -> 16 waves/CU (was 8):
// the single change this round, to hide the s_load/waitcnt latency chains.
// ---------------------------------------------------------------------------
template<int I, int OT, bool FINAL>
__device__ __forceinline__ void gated_body(
    const float2* __restrict__ AX, const float* __restrict__ Ct,
    const float*  __restrict__ M,  const float* __restrict__ W,
    float* __restrict__ out)
{
    constexpr int ICW = I / 8;                  // i extent per wave
    const int tid = threadIdx.x;
    const int b   = tid & 63;
    const int wid = __builtin_amdgcn_readfirstlane(tid >> 6);   // 0..7 uniform
    const int o0  = blockIdx.x * OT;
    const int ibase = wid * ICW;

    float cc[OT], acc[OT];
    const float* __restrict__ mrow[OT];
    const float* __restrict__ wrow[OT];
    #pragma unroll
    for (int oo = 0; oo < OT; ++oo) {
        cc[oo]   = Ct[(o0 + oo) * 64 + b];
        mrow[oo] = M + (size_t)(o0 + oo) * I + ibase;
        wrow[oo] = W + (size_t)(o0 + oo) * I + ibase;
        acc[oo]  = 0.f;
    }
    const float2* __restrict__ axp = AX + (size_t)ibase * 64 + b;

    #pragma unroll 8
    for (int ii = 0; ii < ICW; ++ii) {
        const float2 ax = axp[(size_t)ii * 64];
        #pragma unroll
        for (int oo = 0; oo < OT; ++oo) {
            const float mw = mrow[oo][ii] * wrow[oo][ii];       // s_load * s_load
            const float t  = __builtin_amdgcn_exp2f(-(ax.x * cc[oo]));
            const float s  = __builtin_amdgcn_rcpf(1.f + t);    // inf-safe: ->0
            acc[oo] = fmaf(s, mw * ax.y, acc[oo]);
        }
    }

    __shared__ float red[8][OT][64];
    #pragma unroll
    for (int oo = 0; oo < OT; ++oo) red[wid][oo][b] = acc[oo];
    __syncthreads();
    if (tid < OT * 64) {
        const int oo = tid >> 6, bb = tid & 63;
        float v = 0.f;
        #pragma unroll
        for (int w8 = 0; w8 < 8; ++w8) v += red[w8][oo][bb];
        if (FINAL) out[bb * NOUTD + (o0 + oo)] = v;             // (B, NOUT)
        else       out[((o0 + oo) * 64 + bb) * 2 + 1] = v;      // next AX .y
    }
}

__global__ __launch_bounds__(512, 4) void gated_l1(
    const float2* __restrict__ AX, const float* __restrict__ Ct,
    const float* __restrict__ M, const float* __restrict__ W, float* __restrict__ out)
{ gated_body<NIN, 2, false>(AX, Ct, M, W, out); }

__global__ __launch_bounds__(512, 4) void gated_l2(
    const float2* __restrict__ AX, const float* __restrict__ Ct,
    const float* __restrict__ M, const float* __restrict__ W, float* __restrict__ out)
{ gated_body<H1D, 2, false>(AX, Ct, M, W, out); }

__global__ __launch_bounds__(512, 4) void gated_l3(
    const float2* __restrict__ AX, const float* __restrict__ Ct,
    const float* __restrict__ M, const float* __restrict__ W, float* __restrict__ out)
{ gated_body<H2D, 1, true>(AX, Ct, M, W, out); }

// ---------------------------------------------------------------------------
extern "C" void kernel_launch(void* const* d_in, const int* in_sizes, int n_in,
                              void* d_out, int out_size, void* d_ws, size_t ws_size,
                              hipStream_t stream) {
    (void)in_sizes; (void)n_in; (void)out_size; (void)ws_size;
    const float* x   = (const float*)d_in[0];
    const float* u   = (const float*)d_in[1];
    const float* m0  = (const float*)d_in[2];
    const float* m1  = (const float*)d_in[3];
    const float* m2  = (const float*)d_in[4];
    const float* W0  = (const float*)d_in[5];
    const float* W1  = (const float*)d_in[6];
    const float* W2  = (const float*)d_in[7];
    const float* a0w = (const float*)d_in[8];  const float* a0b = (const float*)d_in[9];
    const float* b0w = (const float*)d_in[10]; const float* b0b = (const float*)d_in[11];
    const float* a1w = (const float*)d_in[12]; const float* a1b = (const float*)d_in[13];
    const float* b1w = (const float*)d_in[14]; const float* b1b = (const float*)d_in[15];
    const float* a2w = (const float*)d_in[16]; const float* a2b = (const float*)d_in[17];
    const float* b2w = (const float*)d_in[18]; const float* b2b = (const float*)d_in[19];

    float* ws  = (float*)d_ws;                 // offsets in floats
    float* AX0 = ws;                           // float2[512*64]   = 65536
    float* AX1 = ws + 65536;                   // float2[1024*64]  = 131072
    float* AX2 = ws + 196608;                  // float2[1024*64]  = 131072
    float* C0t = ws + 327680;                  // 1024*64 = 65536
    float* C1t = ws + 393216;                  // 1024*64 = 65536
    float* C2t = ws + 458752;                  // 512*64  = 32768
    float* out = (float*)d_out;

    prep_kernel<<<328, 256, 0, stream>>>(x, u,
        a0w, a0b, b0w, b0b, a1w, a1b, b1w, b1b, a2w, a2b, b2w, b2b,
        AX0, AX1, AX2, C0t, C1t, C2t);

    // L1: I=512,  O=1024, OT=2 -> 512 blocks; writes AX1 .y
    gated_l1<<<H1D / 2, 512, 0, stream>>>((const float2*)AX0, C0t, m0, W0, AX1);
    // L2: I=1024, O=1024, OT=2 -> 512 blocks; writes AX2 .y
    gated_l2<<<H2D / 2, 512, 0, stream>>>((const float2*)AX1, C1t, m1, W1, AX2);
    // L3: I=1024, O=512,  OT=1 -> 512 blocks; writes d_out (B, NOUT)
    gated_l3<<<NOUTD,   512, 0, stream>>>((const float2*)AX2, C2t, m2, W2, out);
}